// Round 5
// baseline (544.758 us; speedup 1.0000x reference)
//
#include <hip/hip_runtime.h>
#include <hip/hip_bf16.h>
#include <math.h>

#define TB 2
#define TS 2048
#define TT 4096      // tokens = B*S
#define TD 768
#define TH 3072
#define TE 8
#define TASS (2*TT)  // total assignments (top-2, always distinct experts)

typedef short bf16x8 __attribute__((ext_vector_type(8)));
typedef float f32x4 __attribute__((ext_vector_type(4)));

__device__ inline unsigned short f2bfu(float f){
  __hip_bfloat16 h = __float2bfloat16(f);
  union { __hip_bfloat16 h; unsigned short u; } cv; cv.h = h; return cv.u;
}

#define GLOAD_LDS16(g, l) __builtin_amdgcn_global_load_lds( \
    (const __attribute__((address_space(1))) void*)(g), \
    (__attribute__((address_space(3))) void*)(l), 16, 0, 0)

// ---------- x fp32 -> bf16 ----------
__global__ __launch_bounds__(256) void cvt_x_kernel(const float* __restrict__ x,
                                                    unsigned short* __restrict__ xb){
  int i = blockIdx.x*256 + threadIdx.x;          // over TT*TD/4 (exact)
  float4 v = reinterpret_cast<const float4*>(x)[i];
  ushort4 o;
  o.x = f2bfu(v.x); o.y = f2bfu(v.y); o.z = f2bfu(v.z); o.w = f2bfu(v.w);
  reinterpret_cast<ushort4*>(xb)[i] = o;
}

// ---------- weight transpose + convert: in [E][R][C] f32 -> out [E][C][R] bf16 ----------
__global__ __launch_bounds__(256) void transpose_cvt_kernel(const float* __restrict__ in,
    unsigned short* __restrict__ out, int R, int C){
  __shared__ float tile[32][33];
  const size_t eoff = (size_t)blockIdx.z * R * C;
  int c0 = blockIdx.x*32, r0 = blockIdx.y*32;
  #pragma unroll
  for (int i=0;i<4;i++)
    tile[threadIdx.y + i*8][threadIdx.x] =
      in[eoff + (size_t)(r0 + threadIdx.y + i*8)*C + c0 + threadIdx.x];
  __syncthreads();
  #pragma unroll
  for (int i=0;i<4;i++)
    out[eoff + (size_t)(c0 + threadIdx.y + i*8)*R + r0 + threadIdx.x] =
      f2bfu(tile[threadIdx.x][threadIdx.y + i*8]);
}

// ---------- gating: one wave per token ----------
__global__ __launch_bounds__(64) void gating_kernel(const float* __restrict__ x,
    const float* __restrict__ noise, const float* __restrict__ Wg, const float* __restrict__ bg,
    const float* __restrict__ Wn, const float* __restrict__ bn,
    int* __restrict__ counts, int* __restrict__ top2i, float* __restrict__ top2p){
  const int t = blockIdx.x;
  const int lane = threadIdx.x;
  float sg[TE], sn[TE];
  #pragma unroll
  for (int e=0;e<TE;e++){ sg[e]=0.f; sn[e]=0.f; }
  const float* xr = x + (size_t)t*TD;
  for (int d = lane; d < TD; d += 64){
    float xv = xr[d];
    float4 g0 = reinterpret_cast<const float4*>(Wg + d*TE)[0];
    float4 g1 = reinterpret_cast<const float4*>(Wg + d*TE)[1];
    float4 n0 = reinterpret_cast<const float4*>(Wn + d*TE)[0];
    float4 n1 = reinterpret_cast<const float4*>(Wn + d*TE)[1];
    sg[0] += xv*g0.x; sg[1] += xv*g0.y; sg[2] += xv*g0.z; sg[3] += xv*g0.w;
    sg[4] += xv*g1.x; sg[5] += xv*g1.y; sg[6] += xv*g1.z; sg[7] += xv*g1.w;
    sn[0] += xv*n0.x; sn[1] += xv*n0.y; sn[2] += xv*n0.z; sn[3] += xv*n0.w;
    sn[4] += xv*n1.x; sn[5] += xv*n1.y; sn[6] += xv*n1.z; sn[7] += xv*n1.w;
  }
  #pragma unroll
  for (int m = 32; m >= 1; m >>= 1){
    #pragma unroll
    for (int e=0;e<TE;e++){
      sg[e] += __shfl_xor(sg[e], m, 64);
      sn[e] += __shfl_xor(sn[e], m, 64);
    }
  }
  if (lane == 0){
    float h[TE];
    #pragma unroll
    for (int e=0;e<TE;e++){
      float z = sn[e] + bn[e];
      float sp = fmaxf(z, 0.f) + log1pf(expf(-fabsf(z)));   // stable softplus
      h[e] = sg[e] + bg[e] + noise[(size_t)t*TE + e] * sp;
    }
    int i0 = 0;
    #pragma unroll
    for (int e=1;e<TE;e++) if (h[e] > h[i0]) i0 = e;   // strict > : first-index tie-break (jax)
    int i1 = (i0 == 0) ? 1 : 0;
    #pragma unroll
    for (int e=0;e<TE;e++) if (e != i0 && h[e] > h[i1]) i1 = e;
    float v0 = h[i0], v1 = h[i1];
    float p1 = 1.f / (1.f + expf(v0 - v1));   // softmax over {v0,v1}
    float p0 = 1.f - p1;
    atomicAdd(&counts[i0], 1);
    atomicAdd(&counts[i1], 1);
    top2i[t*2]   = i0; top2i[t*2+1] = i1;
    top2p[t*2]   = p0; top2p[t*2+1] = p1;
  }
}

__global__ void init_counts_kernel(int* counts){
  if (threadIdx.x < TE) counts[threadIdx.x] = 0;
}

__global__ void offsets_kernel(const int* __restrict__ counts, int* __restrict__ offs,
                               int* __restrict__ cursor){
  if (threadIdx.x == 0){
    int acc = 0;
    for (int e=0;e<TE;e++){ offs[e] = acc; acc += counts[e]; cursor[e] = 0; }
    offs[TE] = acc;
  }
}

__global__ __launch_bounds__(256) void scatter_kernel(const int* __restrict__ top2i,
    const int* __restrict__ offs, int* __restrict__ cursor,
    int* __restrict__ rowlist, int* __restrict__ tokpos){
  int t = blockIdx.x*256 + threadIdx.x;
  if (t >= TT) return;
  #pragma unroll
  for (int k=0;k<2;k++){
    int e = top2i[t*2+k];
    int p = atomicAdd(&cursor[e], 1);
    int pos = offs[e] + p;
    rowlist[pos] = t;
    tokpos[t*2+k] = pos;
  }
}

// ---------- grouped GEMM: C[m][n] = act(sum_k A[row(m)][k] * Bt[e][n][k] + bias[e][n]) ----------
// 128x128 tile, BK=64, 4 waves (2x2), mfma_f32_16x16x32_bf16.
// Staging: global_load_lds width=16, linear LDS [128][64] bf16.
// Swizzle (rule #21, both-sides): 16B chunk col c8 ^= (row&7) on the SOURCE address,
// read side applies byte ^= (row&7)<<4. row&7 == lane&7 for all fragment reads.
// NKS: compile-time K-split; kseg blocks write CONTIGUOUS partial buffers
// (outf + kseg*TASS*NDIM — caller guarantees 2*TASS*NDIM floats when NKS=2).
template<int KDIM, int NDIM, int NKS, bool GATHER, bool RELU_BF16>
__global__ __launch_bounds__(256) void gemm_moe(
    const unsigned short* __restrict__ A,     // [rows][KDIM] bf16
    const unsigned short* __restrict__ Bt,    // [E][NDIM][KDIM] bf16 (n-major, k-contig)
    const float* __restrict__ bias,           // [E][NDIM]
    const int* __restrict__ rowlist,
    const int* __restrict__ offs,
    const int* __restrict__ counts,
    unsigned short* __restrict__ outbf,       // hid (GEMM1)
    float* __restrict__ outf)                 // ye (GEMM2), partial kseg buffers
{
  const int zz   = blockIdx.z;
  const int e    = (NKS == 1) ? zz : (zz >> 1);
  const int kseg = (NKS == 1) ? 0  : (zz & 1);
  int cnt = counts[e];
  cnt = cnt < 0 ? 0 : (cnt > TASS ? TASS : cnt);        // defensive clamp
  const int mt  = blockIdx.y;
  if (mt*128 >= cnt) return;
  int off = offs[e];
  off = off < 0 ? 0 : (off > TASS ? TASS : off);        // defensive clamp
  const int nt  = blockIdx.x;
  constexpr int KLEN = KDIM / NKS;
  const int kbeg = kseg * KLEN;

  __shared__ alignas(64) unsigned short As[128*64];   // 16 KiB, linear (gload_lds dest)
  __shared__ alignas(64) unsigned short Bs[128*64];

  const int tid  = threadIdx.x;
  const int lane = tid & 63;
  const int w    = tid >> 6;
  const int wm   = w >> 1, wn = w & 1;

  f32x4 acc[4][4];
  {
    f32x4 z = {0.f, 0.f, 0.f, 0.f};
    #pragma unroll
    for (int i=0;i<4;i++)
      #pragma unroll
      for (int j=0;j<4;j++) acc[i][j] = z;
  }

  const unsigned short* Be = Bt + (size_t)e*NDIM*KDIM + (size_t)nt*128*KDIM;

  // Per-thread source offsets (shorts) for the 4 staging chunks; fixed across k0.
  // chunk c = i*256+tid -> LDS row = c>>3, phys col = c&7, LOGICAL col = (c&7)^(row&7).
  size_t a_src[4], b_src[4];
  #pragma unroll
  for (int i=0;i<4;i++){
    int c   = i*256 + tid;
    int row = c >> 3;
    int lc8 = (c & 7) ^ (row & 7);      // inverse-swizzled source chunk
    int grl = mt*128 + row;
    size_t grow;
    if (GATHER){
      int ridx = off + (grl < cnt ? grl : 0);
      ridx = ridx < TASS ? ridx : (TASS - 1);
      int rv = rowlist[ridx];
      rv = (rv >= 0 && rv < TT) ? rv : 0;           // defensive clamp
      grow = (size_t)rv;
    } else {
      size_t g = (size_t)off + (size_t)grl;
      grow = g < (size_t)TASS ? g : (size_t)(TASS - 1);
    }
    a_src[i] = grow * KDIM + (size_t)(lc8 << 3);
    b_src[i] = (size_t)row * KDIM + (size_t)(lc8 << 3);
  }

  const char* Asb = (const char*)As;
  const char* Bsb = (const char*)Bs;
  const int rxor  = (lane & 7) << 4;            // read-side swizzle, constant per lane
  const int arow0 = wm*64 + (lane & 15);        // + f*16
  const int brow0 = wn*64 + (lane & 15);
  const int kgrp  = (lane >> 4) << 4;           // byte offset of this lane-group's k-slice

  for (int k0 = kbeg; k0 < kbeg + KLEN; k0 += 64){
    // wave-uniform LDS base + lane*16 == linear chunk (i*256 + w*64 + lane)
    #pragma unroll
    for (int i=0;i<4;i++){
      unsigned short* ab = &As[(i*256 + w*64) * 8];
      unsigned short* bb = &Bs[(i*256 + w*64) * 8];
      GLOAD_LDS16(A  + a_src[i] + k0, ab);
      GLOAD_LDS16(Be + b_src[i] + k0, bb);
    }
    __syncthreads();   // compiler drains vmcnt before s_barrier
    #pragma unroll
    for (int ks=0; ks<2; ++ks){
      const int kby = ks*64 + kgrp;             // byte offset within row
      bf16x8 af[4], bfr[4];
      #pragma unroll
      for (int f=0; f<4; ++f)
        af[f]  = *reinterpret_cast<const bf16x8*>(Asb + (arow0 + f*16)*128 + (kby ^ rxor));
      #pragma unroll
      for (int f=0; f<4; ++f)
        bfr[f] = *reinterpret_cast<const bf16x8*>(Bsb + (brow0 + f*16)*128 + (kby ^ rxor));
      #pragma unroll
      for (int fm=0; fm<4; ++fm)
        #pragma unroll
        for (int fn=0; fn<4; ++fn)
          acc[fm][fn] = __builtin_amdgcn_mfma_f32_16x16x32_bf16(af[fm], bfr[fn], acc[fm][fn], 0, 0, 0);
    }
    __syncthreads();
  }

  // epilogue: C/D layout col = lane&15, row = (lane>>4)*4 + r  [m89/m91 verified]
  const float* be = bias + (size_t)e*NDIM + (size_t)nt*128;
  float* outseg = outf + (size_t)kseg * TASS * NDIM;   // contiguous partial buffer
  #pragma unroll
  for (int fm=0; fm<4; ++fm){
    const int rbase = wm*64 + fm*16 + ((lane >> 4) << 2);
    #pragma unroll
    for (int fn=0; fn<4; ++fn){
      const int lc = wn*64 + fn*16 + (lane & 15);
      #pragma unroll
      for (int r=0; r<4; ++r){
        int lr = mt*128 + rbase + r;
        if (lr < cnt && off + lr < TASS){
          float v = acc[fm][fn][r];
          if (kseg == 0) v += be[lc];           // bias exactly once per output
          if (RELU_BF16){
            v = fmaxf(v, 0.f);
            outbf[(size_t)(off + lr)*NDIM + nt*128 + lc] = f2bfu(v);
          } else {
            outseg[(size_t)(off + lr)*NDIM + nt*128 + lc] = v;
          }
        }
      }
    }
  }
}

// ---------- combine: out[t] = p0*(ye0+ye1)[pos0] + p1*(ye0+ye1)[pos1] ----------
__global__ __launch_bounds__(256) void combine_kernel(const float* __restrict__ y0,
    const int* __restrict__ tokpos, const float* __restrict__ top2p,
    float* __restrict__ out, int ks2){
  int i = blockIdx.x*256 + threadIdx.x;   // over TT*TD/4 (exact)
  int t  = i / (TD/4);
  int dc = i % (TD/4);
  int pa = tokpos[t*2], pb = tokpos[t*2+1];
  pa = (pa >= 0 && pa < TASS) ? pa : 0;   // defensive clamp
  pb = (pb >= 0 && pb < TASS) ? pb : 0;
  float wa = top2p[t*2], wb = top2p[t*2+1];
  float4 ya = reinterpret_cast<const float4*>(y0)[(size_t)pa*(TD/4) + dc];
  float4 yb = reinterpret_cast<const float4*>(y0)[(size_t)pb*(TD/4) + dc];
  if (ks2){
    const float* y1 = y0 + (size_t)TASS*TD;
    float4 za = reinterpret_cast<const float4*>(y1)[(size_t)pa*(TD/4) + dc];
    float4 zb = reinterpret_cast<const float4*>(y1)[(size_t)pb*(TD/4) + dc];
    ya.x += za.x; ya.y += za.y; ya.z += za.z; ya.w += za.w;
    yb.x += zb.x; yb.y += zb.y; yb.z += zb.z; yb.w += zb.w;
  }
  float4 o;
  o.x = wa*ya.x + wb*yb.x;
  o.y = wa*ya.y + wb*yb.y;
  o.z = wa*ya.z + wb*yb.z;
  o.w = wa*ya.w + wb*yb.w;
  reinterpret_cast<float4*>(out)[i] = o;
}

extern "C" void kernel_launch(void* const* d_in, const int* in_sizes, int n_in,
                              void* d_out, int out_size, void* d_ws, size_t ws_size,
                              hipStream_t stream){
  const float* x     = (const float*)d_in[0];
  const float* noise = (const float*)d_in[1];
  const float* Wg    = (const float*)d_in[2];
  const float* bg    = (const float*)d_in[3];
  const float* Wn    = (const float*)d_in[4];
  const float* bn    = (const float*)d_in[5];
  const float* W1    = (const float*)d_in[6];
  const float* b1    = (const float*)d_in[7];
  const float* W2    = (const float*)d_in[8];
  const float* b2    = (const float*)d_in[9];
  float* out = (float*)d_out;

  // Static workspace budget (all sizes multiples of 256 -> allocator adds no gaps):
  //   xb 6.29MB + W1t 37.75MB + W2t 37.75MB + hid 50.33MB + ye 25.17MB + small ~132KB
  constexpr size_t SZ_XB   = (size_t)TT*TD*2;
  constexpr size_t SZ_W1T  = (size_t)TE*TH*TD*2;
  constexpr size_t SZ_W2T  = (size_t)TE*TD*TH*2;
  constexpr size_t SZ_HID  = (size_t)TASS*TH*2;
  constexpr size_t SZ_YE   = (size_t)TASS*TD*4;
  constexpr size_t SZ_SMALL= 3*256 + 4*((size_t)TT*2*4);  // counts/offs/cursor pads + 4 arrays
  constexpr size_t BASE_NEED = SZ_XB+SZ_W1T+SZ_W2T+SZ_HID+SZ_YE+SZ_SMALL + 4096;
  const int ks2 = (BASE_NEED + SZ_YE <= ws_size) ? 1 : 0;   // ws_size-only -> graph-safe

  char* p = (char*)d_ws;
  auto alloc = [&](size_t bytes)->void*{
    void* r = (void*)p;
    p += (bytes + 255) & ~(size_t)255;
    return r;
  };
  unsigned short* xb  = (unsigned short*)alloc(SZ_XB);
  unsigned short* W1t = (unsigned short*)alloc(SZ_W1T);
  unsigned short* W2t = (unsigned short*)alloc(SZ_W2T);
  unsigned short* hid = (unsigned short*)alloc(SZ_HID);
  float* ye           = (float*)alloc(ks2 ? 2*SZ_YE : SZ_YE);  // kseg partials CONTIGUOUS
  int* counts  = (int*)alloc(TE*4);
  int* offs    = (int*)alloc((TE+1)*4);
  int* cursor  = (int*)alloc(TE*4);
  int* top2i   = (int*)alloc((size_t)TT*2*4);
  float* top2p = (float*)alloc((size_t)TT*2*4);
  int* rowlist = (int*)alloc((size_t)TASS*4);
  int* tokpos  = (int*)alloc((size_t)TT*2*4);
  if ((size_t)(p - (char*)d_ws) > ws_size) return;  // base layout must fit

  cvt_x_kernel<<<TT*TD/4/256, 256, 0, stream>>>(x, xb);
  transpose_cvt_kernel<<<dim3(TH/32, TD/32, TE), dim3(32,8), 0, stream>>>(W1, W1t, TD, TH);
  transpose_cvt_kernel<<<dim3(TD/32, TH/32, TE), dim3(32,8), 0, stream>>>(W2, W2t, TH, TD);
  init_counts_kernel<<<1, 64, 0, stream>>>(counts);
  gating_kernel<<<TT, 64, 0, stream>>>(x, noise, Wg, bg, Wn, bn, counts, top2i, top2p);
  offsets_kernel<<<1, 64, 0, stream>>>(counts, offs, cursor);
  scatter_kernel<<<TT/256, 256, 0, stream>>>(top2i, offs, cursor, rowlist, tokpos);

  gemm_moe<TD, TH, 1, true,  true ><<<dim3(TH/128, 32, TE), 256, 0, stream>>>(
      xb, W1t, b1, rowlist, offs, counts, hid, nullptr);
  if (ks2){
    gemm_moe<TH, TD, 2, false, false><<<dim3(TD/128, 32, TE*2), 256, 0, stream>>>(
        hid, W2t, b2, nullptr, offs, counts, nullptr, ye);
  } else {
    gemm_moe<TH, TD, 1, false, false><<<dim3(TD/128, 32, TE), 256, 0, stream>>>(
        hid, W2t, b2, nullptr, offs, counts, nullptr, ye);
  }

  combine_kernel<<<TT*TD/4/256, 256, 0, stream>>>(ye, tokpos, top2p, out, ks2);
}

// Round 7
// 454.270 us; speedup vs baseline: 1.1992x; 1.1992x over previous
//
#include <hip/hip_runtime.h>
#include <hip/hip_bf16.h>
#include <math.h>

#define TB 2
#define TS 2048
#define TT 4096      // tokens = B*S
#define TD 768
#define TH 3072
#define TE 8
#define TASS (2*TT)  // total assignments (top-2, always distinct experts)

typedef short bf16x8 __attribute__((ext_vector_type(8)));
typedef float f32x4 __attribute__((ext_vector_type(4)));

__device__ inline unsigned short f2bfu(float f){
  __hip_bfloat16 h = __float2bfloat16(f);
  union { __hip_bfloat16 h; unsigned short u; } cv; cv.h = h; return cv.u;
}

#define GLOAD_LDS16(g, l) __builtin_amdgcn_global_load_lds( \
    (const __attribute__((address_space(1))) void*)(g), \
    (__attribute__((address_space(3))) void*)(l), 16, 0, 0)

// ---------- x fp32 -> bf16 ----------
__global__ __launch_bounds__(256) void cvt_x_kernel(const float* __restrict__ x,
                                                    unsigned short* __restrict__ xb){
  int i = blockIdx.x*256 + threadIdx.x;          // over TT*TD/4 (exact)
  float4 v = reinterpret_cast<const float4*>(x)[i];
  ushort4 o;
  o.x = f2bfu(v.x); o.y = f2bfu(v.y); o.z = f2bfu(v.z); o.w = f2bfu(v.w);
  reinterpret_cast<ushort4*>(xb)[i] = o;
}

// ---------- weight transpose + convert: in [E][R][C] f32 -> out [E][C][R] bf16 ----------
__global__ __launch_bounds__(256) void transpose_cvt_kernel(const float* __restrict__ in,
    unsigned short* __restrict__ out, int R, int C){
  __shared__ float tile[32][33];
  const size_t eoff = (size_t)blockIdx.z * R * C;
  int c0 = blockIdx.x*32, r0 = blockIdx.y*32;
  #pragma unroll
  for (int i=0;i<4;i++)
    tile[threadIdx.y + i*8][threadIdx.x] =
      in[eoff + (size_t)(r0 + threadIdx.y + i*8)*C + c0 + threadIdx.x];
  __syncthreads();
  #pragma unroll
  for (int i=0;i<4;i++)
    out[eoff + (size_t)(c0 + threadIdx.y + i*8)*R + r0 + threadIdx.x] =
      f2bfu(tile[threadIdx.x][threadIdx.y + i*8]);
}

// ---------- gating: one wave per token, 4 tokens per block, NO ATOMICS ----------
__global__ __launch_bounds__(256) void gating_kernel(const float* __restrict__ x,
    const float* __restrict__ noise, const float* __restrict__ Wg, const float* __restrict__ bg,
    const float* __restrict__ Wn, const float* __restrict__ bn,
    int* __restrict__ top2i, float* __restrict__ top2p){
  const int wave = threadIdx.x >> 6;
  const int lane = threadIdx.x & 63;
  const int t = blockIdx.x*4 + wave;
  float sg[TE], sn[TE];
  #pragma unroll
  for (int e=0;e<TE;e++){ sg[e]=0.f; sn[e]=0.f; }
  const float* xr = x + (size_t)t*TD;
  for (int d = lane; d < TD; d += 64){
    float xv = xr[d];
    float4 g0 = reinterpret_cast<const float4*>(Wg + d*TE)[0];
    float4 g1 = reinterpret_cast<const float4*>(Wg + d*TE)[1];
    float4 n0 = reinterpret_cast<const float4*>(Wn + d*TE)[0];
    float4 n1 = reinterpret_cast<const float4*>(Wn + d*TE)[1];
    sg[0] += xv*g0.x; sg[1] += xv*g0.y; sg[2] += xv*g0.z; sg[3] += xv*g0.w;
    sg[4] += xv*g1.x; sg[5] += xv*g1.y; sg[6] += xv*g1.z; sg[7] += xv*g1.w;
    sn[0] += xv*n0.x; sn[1] += xv*n0.y; sn[2] += xv*n0.z; sn[3] += xv*n0.w;
    sn[4] += xv*n1.x; sn[5] += xv*n1.y; sn[6] += xv*n1.z; sn[7] += xv*n1.w;
  }
  #pragma unroll
  for (int m = 32; m >= 1; m >>= 1){
    #pragma unroll
    for (int e=0;e<TE;e++){
      sg[e] += __shfl_xor(sg[e], m, 64);
      sn[e] += __shfl_xor(sn[e], m, 64);
    }
  }
  if (lane == 0){
    float h[TE];
    #pragma unroll
    for (int e=0;e<TE;e++){
      float z = sn[e] + bn[e];
      float sp = fmaxf(z, 0.f) + log1pf(expf(-fabsf(z)));   // stable softplus
      h[e] = sg[e] + bg[e] + noise[(size_t)t*TE + e] * sp;
    }
    int i0 = 0;
    #pragma unroll
    for (int e=1;e<TE;e++) if (h[e] > h[i0]) i0 = e;   // strict > : first-index tie-break (jax)
    int i1 = (i0 == 0) ? 1 : 0;
    #pragma unroll
    for (int e=0;e<TE;e++) if (e != i0 && h[e] > h[i1]) i1 = e;
    float v0 = h[i0], v1 = h[i1];
    float p1 = 1.f / (1.f + expf(v0 - v1));   // softmax over {v0,v1}
    float p0 = 1.f - p1;
    top2i[t*2]   = i0; top2i[t*2+1] = i1;
    top2p[t*2]   = p0; top2p[t*2+1] = p1;
  }
}

// ---------- route: single block, 8 waves; wave w owns expert w. Atomic-free, deterministic.
// Pass 1: count matches per expert (ballot+popc). Prefix -> offs. Pass 2: rank-assign positions.
__global__ __launch_bounds__(512) void route_kernel(const int* __restrict__ top2i,
    int* __restrict__ counts, int* __restrict__ offs,
    int* __restrict__ rowlist, int* __restrict__ tokpos){
  const int w    = threadIdx.x >> 6;    // expert id
  const int lane = threadIdx.x & 63;
  __shared__ int cnt_lds[TE];
  __shared__ int off_lds[TE+1];

  int cnt = 0;
  for (int base = 0; base < TASS; base += 64){
    int e = top2i[base + lane];
    unsigned long long m = __ballot(e == w);
    cnt += (int)__popcll(m);
  }
  if (lane == 0) cnt_lds[w] = cnt;
  __syncthreads();
  if (threadIdx.x == 0){
    int acc = 0;
    #pragma unroll
    for (int e=0;e<TE;e++){ off_lds[e] = acc; acc += cnt_lds[e]; }
    off_lds[TE] = acc;
    #pragma unroll
    for (int e=0;e<TE;e++){ counts[e] = cnt_lds[e]; offs[e] = off_lds[e]; }
    offs[TE] = acc;
  }
  __syncthreads();

  const unsigned long long below = (lane == 0) ? 0ull : (~0ull >> (64 - lane));
  int run = off_lds[w];
  for (int base = 0; base < TASS; base += 64){
    int e = top2i[base + lane];
    unsigned long long m = __ballot(e == w);
    if (e == w){
      int pos = run + (int)__popcll(m & below);
      rowlist[pos] = (base + lane) >> 1;      // token id of assignment slot
      tokpos[base + lane] = pos;
    }
    run += (int)__popcll(m);
  }
}

// ---------- grouped GEMM: C[m][n] = act(sum_k A[row(m)][k] * Bt[e][n][k] + bias[e][n]) ----------
// 128x128 tile, BK=64, 4 waves (2x2), mfma_f32_16x16x32_bf16.
// Staging: global_load_lds width=16, linear LDS [128][64] bf16.
// Swizzle (rule #21, both-sides): 16B chunk col c8 ^= (row&7) on the SOURCE address,
// read side applies byte ^= (row&7)<<4. row&7 == lane&7 for all fragment reads.
// NKS: compile-time K-split; kseg blocks write CONTIGUOUS partial buffers
// (outf + kseg*TASS*NDIM — caller guarantees 2*TASS*NDIM floats when NKS=2).
template<int KDIM, int NDIM, int NKS, bool GATHER, bool RELU_BF16>
__global__ __launch_bounds__(256) void gemm_moe(
    const unsigned short* __restrict__ A,     // [rows][KDIM] bf16
    const unsigned short* __restrict__ Bt,    // [E][NDIM][KDIM] bf16 (n-major, k-contig)
    const float* __restrict__ bias,           // [E][NDIM]
    const int* __restrict__ rowlist,
    const int* __restrict__ offs,
    const int* __restrict__ counts,
    unsigned short* __restrict__ outbf,       // hid (GEMM1)
    float* __restrict__ outf)                 // ye (GEMM2), partial kseg buffers
{
  const int zz   = blockIdx.z;
  const int e    = (NKS == 1) ? zz : (zz >> 1);
  const int kseg = (NKS == 1) ? 0  : (zz & 1);
  int cnt = counts[e];
  cnt = cnt < 0 ? 0 : (cnt > TASS ? TASS : cnt);        // defensive clamp
  const int mt  = blockIdx.y;
  if (mt*128 >= cnt) return;
  int off = offs[e];
  off = off < 0 ? 0 : (off > TASS ? TASS : off);        // defensive clamp
  const int nt  = blockIdx.x;
  constexpr int KLEN = KDIM / NKS;
  const int kbeg = kseg * KLEN;

  __shared__ alignas(64) unsigned short As[128*64];   // 16 KiB, linear (gload_lds dest)
  __shared__ alignas(64) unsigned short Bs[128*64];

  const int tid  = threadIdx.x;
  const int lane = tid & 63;
  const int w    = tid >> 6;
  const int wm   = w >> 1, wn = w & 1;

  f32x4 acc[4][4];
  {
    f32x4 z = {0.f, 0.f, 0.f, 0.f};
    #pragma unroll
    for (int i=0;i<4;i++)
      #pragma unroll
      for (int j=0;j<4;j++) acc[i][j] = z;
  }

  const unsigned short* Be = Bt + (size_t)e*NDIM*KDIM + (size_t)nt*128*KDIM;

  // Per-thread source offsets (shorts) for the 4 staging chunks; fixed across k0.
  // chunk c = i*256+tid -> LDS row = c>>3, phys col = c&7, LOGICAL col = (c&7)^(row&7).
  size_t a_src[4], b_src[4];
  #pragma unroll
  for (int i=0;i<4;i++){
    int c   = i*256 + tid;
    int row = c >> 3;
    int lc8 = (c & 7) ^ (row & 7);      // inverse-swizzled source chunk
    int grl = mt*128 + row;
    size_t grow;
    if (GATHER){
      int ridx = off + (grl < cnt ? grl : 0);
      ridx = ridx < TASS ? ridx : (TASS - 1);
      int rv = rowlist[ridx];
      rv = (rv >= 0 && rv < TT) ? rv : 0;           // defensive clamp
      grow = (size_t)rv;
    } else {
      size_t g = (size_t)off + (size_t)grl;
      grow = g < (size_t)TASS ? g : (size_t)(TASS - 1);
    }
    a_src[i] = grow * KDIM + (size_t)(lc8 << 3);
    b_src[i] = (size_t)row * KDIM + (size_t)(lc8 << 3);
  }

  const char* Asb = (const char*)As;
  const char* Bsb = (const char*)Bs;
  const int rxor  = (lane & 7) << 4;            // read-side swizzle, constant per lane
  const int arow0 = wm*64 + (lane & 15);        // + f*16
  const int brow0 = wn*64 + (lane & 15);
  const int kgrp  = (lane >> 4) << 4;           // byte offset of this lane-group's k-slice

  for (int k0 = kbeg; k0 < kbeg + KLEN; k0 += 64){
    // wave-uniform LDS base + lane*16 == linear chunk (i*256 + w*64 + lane)
    #pragma unroll
    for (int i=0;i<4;i++){
      unsigned short* ab = &As[(i*256 + w*64) * 8];
      unsigned short* bb = &Bs[(i*256 + w*64) * 8];
      GLOAD_LDS16(A  + a_src[i] + k0, ab);
      GLOAD_LDS16(Be + b_src[i] + k0, bb);
    }
    __syncthreads();   // compiler drains vmcnt before s_barrier
    #pragma unroll
    for (int ks=0; ks<2; ++ks){
      const int kby = ks*64 + kgrp;             // byte offset within row
      bf16x8 af[4], bfr[4];
      #pragma unroll
      for (int f=0; f<4; ++f)
        af[f]  = *reinterpret_cast<const bf16x8*>(Asb + (arow0 + f*16)*128 + (kby ^ rxor));
      #pragma unroll
      for (int f=0; f<4; ++f)
        bfr[f] = *reinterpret_cast<const bf16x8*>(Bsb + (brow0 + f*16)*128 + (kby ^ rxor));
      #pragma unroll
      for (int fm=0; fm<4; ++fm)
        #pragma unroll
        for (int fn=0; fn<4; ++fn)
          acc[fm][fn] = __builtin_amdgcn_mfma_f32_16x16x32_bf16(af[fm], bfr[fn], acc[fm][fn], 0, 0, 0);
    }
    __syncthreads();
  }

  // epilogue: C/D layout col = lane&15, row = (lane>>4)*4 + r  [m89/m91 verified]
  const float* be = bias + (size_t)e*NDIM + (size_t)nt*128;
  float* outseg = outf + (size_t)kseg * TASS * NDIM;   // contiguous partial buffer
  #pragma unroll
  for (int fm=0; fm<4; ++fm){
    const int rbase = wm*64 + fm*16 + ((lane >> 4) << 2);
    #pragma unroll
    for (int fn=0; fn<4; ++fn){
      const int lc = wn*64 + fn*16 + (lane & 15);
      #pragma unroll
      for (int r=0; r<4; ++r){
        int lr = mt*128 + rbase + r;
        if (lr < cnt && off + lr < TASS){
          float v = acc[fm][fn][r];
          if (kseg == 0) v += be[lc];           // bias exactly once per output
          if (RELU_BF16){
            v = fmaxf(v, 0.f);
            outbf[(size_t)(off + lr)*NDIM + nt*128 + lc] = f2bfu(v);
          } else {
            outseg[(size_t)(off + lr)*NDIM + nt*128 + lc] = v;
          }
        }
      }
    }
  }
}

// ---------- combine: out[t] = p0*(ye0+ye1)[pos0] + p1*(ye0+ye1)[pos1] ----------
__global__ __launch_bounds__(256) void combine_kernel(const float* __restrict__ y0,
    const int* __restrict__ tokpos, const float* __restrict__ top2p,
    float* __restrict__ out, int ks2){
  int i = blockIdx.x*256 + threadIdx.x;   // over TT*TD/4 (exact)
  int t  = i / (TD/4);
  int dc = i % (TD/4);
  int pa = tokpos[t*2], pb = tokpos[t*2+1];
  pa = (pa >= 0 && pa < TASS) ? pa : 0;   // defensive clamp
  pb = (pb >= 0 && pb < TASS) ? pb : 0;
  float wa = top2p[t*2], wb = top2p[t*2+1];
  float4 ya = reinterpret_cast<const float4*>(y0)[(size_t)pa*(TD/4) + dc];
  float4 yb = reinterpret_cast<const float4*>(y0)[(size_t)pb*(TD/4) + dc];
  if (ks2){
    const float* y1 = y0 + (size_t)TASS*TD;
    float4 za = reinterpret_cast<const float4*>(y1)[(size_t)pa*(TD/4) + dc];
    float4 zb = reinterpret_cast<const float4*>(y1)[(size_t)pb*(TD/4) + dc];
    ya.x += za.x; ya.y += za.y; ya.z += za.z; ya.w += za.w;
    yb.x += zb.x; yb.y += zb.y; yb.z += zb.z; yb.w += zb.w;
  }
  float4 o;
  o.x = wa*ya.x + wb*yb.x;
  o.y = wa*ya.y + wb*yb.y;
  o.z = wa*ya.z + wb*yb.z;
  o.w = wa*ya.w + wb*yb.w;
  reinterpret_cast<float4*>(out)[i] = o;
}

extern "C" void kernel_launch(void* const* d_in, const int* in_sizes, int n_in,
                              void* d_out, int out_size, void* d_ws, size_t ws_size,
                              hipStream_t stream){
  const float* x     = (const float*)d_in[0];
  const float* noise = (const float*)d_in[1];
  const float* Wg    = (const float*)d_in[2];
  const float* bg    = (const float*)d_in[3];
  const float* Wn    = (const float*)d_in[4];
  const float* bn    = (const float*)d_in[5];
  const float* W1    = (const float*)d_in[6];
  const float* b1    = (const float*)d_in[7];
  const float* W2    = (const float*)d_in[8];
  const float* b2    = (const float*)d_in[9];
  float* out = (float*)d_out;

  // Static workspace budget (all sizes multiples of 256 -> allocator adds no gaps):
  constexpr size_t SZ_XB   = (size_t)TT*TD*2;
  constexpr size_t SZ_W1T  = (size_t)TE*TH*TD*2;
  constexpr size_t SZ_W2T  = (size_t)TE*TD*TH*2;
  constexpr size_t SZ_HID  = (size_t)TASS*TH*2;
  constexpr size_t SZ_YE   = (size_t)TASS*TD*4;
  constexpr size_t SZ_SMALL= 2*256 + 4*((size_t)TT*2*4);
  constexpr size_t BASE_NEED = SZ_XB+SZ_W1T+SZ_W2T+SZ_HID+SZ_YE+SZ_SMALL + 4096;
  const int ks2 = (BASE_NEED + SZ_YE <= ws_size) ? 1 : 0;   // ws_size-only -> graph-safe

  char* p = (char*)d_ws;
  auto alloc = [&](size_t bytes)->void*{
    void* r = (void*)p;
    p += (bytes + 255) & ~(size_t)255;
    return r;
  };
  unsigned short* xb  = (unsigned short*)alloc(SZ_XB);
  unsigned short* W1t = (unsigned short*)alloc(SZ_W1T);
  unsigned short* W2t = (unsigned short*)alloc(SZ_W2T);
  unsigned short* hid = (unsigned short*)alloc(SZ_HID);
  float* ye           = (float*)alloc(ks2 ? 2*SZ_YE : SZ_YE);  // kseg partials CONTIGUOUS
  int* counts  = (int*)alloc(TE*4);
  int* offs    = (int*)alloc((TE+1)*4);
  int* top2i   = (int*)alloc((size_t)TT*2*4);
  float* top2p = (float*)alloc((size_t)TT*2*4);
  int* rowlist = (int*)alloc((size_t)TASS*4);
  int* tokpos  = (int*)alloc((size_t)TT*2*4);
  if ((size_t)(p - (char*)d_ws) > ws_size) return;  // base layout must fit

  cvt_x_kernel<<<TT*TD/4/256, 256, 0, stream>>>(x, xb);
  transpose_cvt_kernel<<<dim3(TH/32, TD/32, TE), dim3(32,8), 0, stream>>>(W1, W1t, TD, TH);
  transpose_cvt_kernel<<<dim3(TD/32, TH/32, TE), dim3(32,8), 0, stream>>>(W2, W2t, TH, TD);
  gating_kernel<<<TT/4, 256, 0, stream>>>(x, noise, Wg, bg, Wn, bn, top2i, top2p);
  route_kernel<<<1, 512, 0, stream>>>(top2i, counts, offs, rowlist, tokpos);

  gemm_moe<TD, TH, 1, true,  true ><<<dim3(TH/128, 32, TE), 256, 0, stream>>>(
      xb, W1t, b1, rowlist, offs, counts, hid, nullptr);
  if (ks2){
    gemm_moe<TH, TD, 2, false, false><<<dim3(TD/128, 32, TE*2), 256, 0, stream>>>(
        hid, W2t, b2, nullptr, offs, counts, nullptr, ye);
  } else {
    gemm_moe<TH, TD, 1, false, false><<<dim3(TD/128, 32, TE), 256, 0, stream>>>(
        hid, W2t, b2, nullptr, offs, counts, nullptr, ye);
  }

  combine_kernel<<<TT*TD/4/256, 256, 0, stream>>>(ye, tokpos, top2p, out, ks2);
}

// Round 10
// 432.519 us; speedup vs baseline: 1.2595x; 1.0503x over previous
//
#include <hip/hip_runtime.h>
#include <hip/hip_bf16.h>
#include <math.h>

#define TB 2
#define TS 2048
#define TT 4096      // tokens = B*S
#define TD 768
#define TH 3072
#define TE 8
#define TASS (2*TT)  // total assignments (top-2, always distinct experts)

typedef short bf16x8 __attribute__((ext_vector_type(8)));
typedef float f32x4 __attribute__((ext_vector_type(4)));

__device__ inline unsigned short f2bfu(float f){
  __hip_bfloat16 h = __float2bfloat16(f);
  union { __hip_bfloat16 h; unsigned short u; } cv; cv.h = h; return cv.u;
}

#define GLOAD_LDS16(g, l) __builtin_amdgcn_global_load_lds( \
    (const __attribute__((address_space(1))) void*)(g), \
    (__attribute__((address_space(3))) void*)(l), 16, 0, 0)

// ---------- x fp32 -> bf16 ----------
__global__ __launch_bounds__(256) void cvt_x_kernel(const float* __restrict__ x,
                                                    unsigned short* __restrict__ xb){
  int i = blockIdx.x*256 + threadIdx.x;          // over TT*TD/4 (exact)
  float4 v = reinterpret_cast<const float4*>(x)[i];
  ushort4 o;
  o.x = f2bfu(v.x); o.y = f2bfu(v.y); o.z = f2bfu(v.z); o.w = f2bfu(v.w);
  reinterpret_cast<ushort4*>(xb)[i] = o;
}

// ---------- weight transpose + convert: in [E][R][C] f32 -> out [E][C][R] bf16 ----------
__global__ __launch_bounds__(256) void transpose_cvt_kernel(const float* __restrict__ in,
    unsigned short* __restrict__ out, int R, int C){
  __shared__ float tile[32][33];
  const size_t eoff = (size_t)blockIdx.z * R * C;
  int c0 = blockIdx.x*32, r0 = blockIdx.y*32;
  #pragma unroll
  for (int i=0;i<4;i++)
    tile[threadIdx.y + i*8][threadIdx.x] =
      in[eoff + (size_t)(r0 + threadIdx.y + i*8)*C + c0 + threadIdx.x];
  __syncthreads();
  #pragma unroll
  for (int i=0;i<4;i++)
    out[eoff + (size_t)(c0 + threadIdx.y + i*8)*R + r0 + threadIdx.x] =
      f2bfu(tile[threadIdx.x][threadIdx.y + i*8]);
}

// ---------- gating: one wave per token, 4 tokens per block, NO ATOMICS ----------
__global__ __launch_bounds__(256) void gating_kernel(const float* __restrict__ x,
    const float* __restrict__ noise, const float* __restrict__ Wg, const float* __restrict__ bg,
    const float* __restrict__ Wn, const float* __restrict__ bn,
    int* __restrict__ top2i, float* __restrict__ top2p){
  const int wave = threadIdx.x >> 6;
  const int lane = threadIdx.x & 63;
  const int t = blockIdx.x*4 + wave;
  float sg[TE], sn[TE];
  #pragma unroll
  for (int e=0;e<TE;e++){ sg[e]=0.f; sn[e]=0.f; }
  const float* xr = x + (size_t)t*TD;
  for (int d = lane; d < TD; d += 64){
    float xv = xr[d];
    float4 g0 = reinterpret_cast<const float4*>(Wg + d*TE)[0];
    float4 g1 = reinterpret_cast<const float4*>(Wg + d*TE)[1];
    float4 n0 = reinterpret_cast<const float4*>(Wn + d*TE)[0];
    float4 n1 = reinterpret_cast<const float4*>(Wn + d*TE)[1];
    sg[0] += xv*g0.x; sg[1] += xv*g0.y; sg[2] += xv*g0.z; sg[3] += xv*g0.w;
    sg[4] += xv*g1.x; sg[5] += xv*g1.y; sg[6] += xv*g1.z; sg[7] += xv*g1.w;
    sn[0] += xv*n0.x; sn[1] += xv*n0.y; sn[2] += xv*n0.z; sn[3] += xv*n0.w;
    sn[4] += xv*n1.x; sn[5] += xv*n1.y; sn[6] += xv*n1.z; sn[7] += xv*n1.w;
  }
  #pragma unroll
  for (int m = 32; m >= 1; m >>= 1){
    #pragma unroll
    for (int e=0;e<TE;e++){
      sg[e] += __shfl_xor(sg[e], m, 64);
      sn[e] += __shfl_xor(sn[e], m, 64);
    }
  }
  if (lane == 0){
    float h[TE];
    #pragma unroll
    for (int e=0;e<TE;e++){
      float z = sn[e] + bn[e];
      float sp = fmaxf(z, 0.f) + log1pf(expf(-fabsf(z)));   // stable softplus
      h[e] = sg[e] + bg[e] + noise[(size_t)t*TE + e] * sp;
    }
    int i0 = 0;
    #pragma unroll
    for (int e=1;e<TE;e++) if (h[e] > h[i0]) i0 = e;   // strict > : first-index tie-break (jax)
    int i1 = (i0 == 0) ? 1 : 0;
    #pragma unroll
    for (int e=0;e<TE;e++) if (e != i0 && h[e] > h[i1]) i1 = e;
    float v0 = h[i0], v1 = h[i1];
    float p1 = 1.f / (1.f + expf(v0 - v1));   // softmax over {v0,v1}
    float p0 = 1.f - p1;
    top2i[t*2]   = i0; top2i[t*2+1] = i1;
    top2p[t*2]   = p0; top2p[t*2+1] = p1;
  }
}

// ---------- route: single block, 8 waves; wave w owns expert w. Atomic-free, deterministic.
// top2i staged to LDS once (coalesced int4) -> ballot passes read LDS, not global.
__global__ __launch_bounds__(512) void route_kernel(const int* __restrict__ top2i,
    int* __restrict__ counts, int* __restrict__ offs,
    int* __restrict__ rowlist, int* __restrict__ tokpos){
  __shared__ int e_lds[TASS];          // 32 KiB
  __shared__ int cnt_lds[TE];
  __shared__ int off_lds[TE+1];
  for (int i = threadIdx.x; i < TASS/4; i += 512)
    reinterpret_cast<int4*>(e_lds)[i] = reinterpret_cast<const int4*>(top2i)[i];
  __syncthreads();

  const int w    = threadIdx.x >> 6;    // expert id
  const int lane = threadIdx.x & 63;

  int cnt = 0;
  for (int base = 0; base < TASS; base += 64){
    unsigned long long m = __ballot(e_lds[base + lane] == w);
    cnt += (int)__popcll(m);
  }
  if (lane == 0) cnt_lds[w] = cnt;
  __syncthreads();
  if (threadIdx.x == 0){
    int acc = 0;
    #pragma unroll
    for (int e=0;e<TE;e++){ off_lds[e] = acc; acc += cnt_lds[e]; }
    off_lds[TE] = acc;
    #pragma unroll
    for (int e=0;e<TE;e++){ counts[e] = cnt_lds[e]; offs[e] = off_lds[e]; }
    offs[TE] = acc;
  }
  __syncthreads();

  const unsigned long long below = (lane == 0) ? 0ull : (~0ull >> (64 - lane));
  int run = off_lds[w];
  for (int base = 0; base < TASS; base += 64){
    int e = e_lds[base + lane];
    unsigned long long m = __ballot(e == w);
    if (e == w){
      int pos = run + (int)__popcll(m & below);
      rowlist[pos] = (base + lane) >> 1;      // token id of assignment slot
      tokpos[base + lane] = pos;
    }
    run += (int)__popcll(m);
  }
}

// ---------- grouped GEMM: C[m][n] = act(sum_k A[row(m)][k] * Bt[e][n][k] + bias[e][n]) ----------
// 128x128 tile, BK=64, 4 waves (2x2), mfma_f32_16x16x32_bf16.
// 2-PHASE double-buffered LDS (T3 minimum recipe): STAGE(next) issued BEFORE compute(cur);
// ONE __syncthreads per K-step (its vmcnt(0) drain = RAW for next buf, barrier = WAR for cur).
// Staging: global_load_lds width=16, linear LDS [128][64] bf16 per buffer.
// Swizzle (rule #21, both-sides): source chunk c8 ^= (row&7); read byte ^= (lane&7)<<4.
// NKS: compile-time K-split; kseg blocks write CONTIGUOUS partial buffers.
template<int KDIM, int NDIM, int NKS, bool GATHER, bool RELU_BF16>
__global__ __launch_bounds__(256) void gemm_moe(
    const unsigned short* __restrict__ A,     // [rows][KDIM] bf16
    const unsigned short* __restrict__ Bt,    // [E][NDIM][KDIM] bf16 (n-major, k-contig)
    const float* __restrict__ bias,           // [E][NDIM]
    const int* __restrict__ rowlist,
    const int* __restrict__ offs,
    const int* __restrict__ counts,
    unsigned short* __restrict__ outbf,       // hid (GEMM1)
    float* __restrict__ outf)                 // ye (GEMM2), partial kseg buffers
{
  const int zz   = blockIdx.z;
  const int e    = (NKS == 1) ? zz : (zz >> 1);
  const int kseg = (NKS == 1) ? 0  : (zz & 1);
  int cnt = counts[e];
  cnt = cnt < 0 ? 0 : (cnt > TASS ? TASS : cnt);        // defensive clamp
  const int mt  = blockIdx.y;
  if (mt*128 >= cnt) return;
  int off = offs[e];
  off = off < 0 ? 0 : (off > TASS ? TASS : off);        // defensive clamp
  const int nt  = blockIdx.x;
  constexpr int KLEN   = KDIM / NKS;
  constexpr int NSTEPS = KLEN / 64;
  const int kbeg = kseg * KLEN;

  __shared__ alignas(64) unsigned short As[2][128*64];  // 2 x 16 KiB, linear (gload_lds dest)
  __shared__ alignas(64) unsigned short Bs[2][128*64];

  const int tid  = threadIdx.x;
  const int lane = tid & 63;
  const int w    = tid >> 6;
  const int wm   = w >> 1, wn = w & 1;

  f32x4 acc[4][4];
  {
    f32x4 z = {0.f, 0.f, 0.f, 0.f};
    #pragma unroll
    for (int i=0;i<4;i++)
      #pragma unroll
      for (int j=0;j<4;j++) acc[i][j] = z;
  }

  const unsigned short* Be = Bt + (size_t)e*NDIM*KDIM + (size_t)nt*128*KDIM;

  // Per-thread source offsets for the 4 staging chunks; fixed across k0.
  // chunk c = i*256+tid -> LDS row = c>>3, phys col = c&7, LOGICAL col = (c&7)^(row&7).
  size_t a_src[4], b_src[4];
  #pragma unroll
  for (int i=0;i<4;i++){
    int c   = i*256 + tid;
    int row = c >> 3;
    int lc8 = (c & 7) ^ (row & 7);      // inverse-swizzled source chunk
    int grl = mt*128 + row;
    size_t grow;
    if (GATHER){
      int ridx = off + (grl < cnt ? grl : 0);
      ridx = ridx < TASS ? ridx : (TASS - 1);
      int rv = rowlist[ridx];
      rv = (rv >= 0 && rv < TT) ? rv : 0;           // defensive clamp
      grow = (size_t)rv;
    } else {
      size_t g = (size_t)off + (size_t)grl;
      grow = g < (size_t)TASS ? g : (size_t)(TASS - 1);
    }
    a_src[i] = grow * KDIM + (size_t)(lc8 << 3);
    b_src[i] = (size_t)row * KDIM + (size_t)(lc8 << 3);
  }

  const int rxor  = (lane & 7) << 4;            // read-side swizzle, constant per lane
  const int arow0 = wm*64 + (lane & 15);        // + f*16
  const int brow0 = wn*64 + (lane & 15);
  const int kgrp  = (lane >> 4) << 4;           // byte offset of this lane-group's k-slice

  auto STAGE = [&](int buf, int k0){
    #pragma unroll
    for (int i=0;i<4;i++){
      GLOAD_LDS16(A  + a_src[i] + k0, &As[buf][(i*256 + w*64) * 8]);
      GLOAD_LDS16(Be + b_src[i] + k0, &Bs[buf][(i*256 + w*64) * 8]);
    }
  };
  auto COMPUTE = [&](int buf){
    const char* Asb = (const char*)&As[buf][0];
    const char* Bsb = (const char*)&Bs[buf][0];
    #pragma unroll
    for (int ks=0; ks<2; ++ks){
      const int kby = ks*64 + kgrp;             // byte offset within row
      bf16x8 af[4], bfr[4];
      #pragma unroll
      for (int f=0; f<4; ++f)
        af[f]  = *reinterpret_cast<const bf16x8*>(Asb + (arow0 + f*16)*128 + (kby ^ rxor));
      #pragma unroll
      for (int f=0; f<4; ++f)
        bfr[f] = *reinterpret_cast<const bf16x8*>(Bsb + (brow0 + f*16)*128 + (kby ^ rxor));
      #pragma unroll
      for (int fm=0; fm<4; ++fm)
        #pragma unroll
        for (int fn=0; fn<4; ++fn)
          acc[fm][fn] = __builtin_amdgcn_mfma_f32_16x16x32_bf16(af[fm], bfr[fn], acc[fm][fn], 0, 0, 0);
    }
  };

  // 2-phase pipeline: one barrier per K-step, loads overlap compute.
  STAGE(0, kbeg);
  __syncthreads();
  int cur = 0;
  #pragma unroll 2
  for (int t = 0; t < NSTEPS-1; ++t){
    STAGE(cur^1, kbeg + (t+1)*64);
    COMPUTE(cur);
    __syncthreads();   // drains this wave's gload_lds (next buf ready) + WAR fence for cur
    cur ^= 1;
  }
  COMPUTE(cur);

  // epilogue: C/D layout col = lane&15, row = (lane>>4)*4 + r  [m89/m91 verified]
  const float* be = bias + (size_t)e*NDIM + (size_t)nt*128;
  float* outseg = outf + (size_t)kseg * TASS * NDIM;   // contiguous partial buffer
  #pragma unroll
  for (int fm=0; fm<4; ++fm){
    const int rbase = wm*64 + fm*16 + ((lane >> 4) << 2);
    #pragma unroll
    for (int fn=0; fn<4; ++fn){
      const int lc = wn*64 + fn*16 + (lane & 15);
      #pragma unroll
      for (int r=0; r<4; ++r){
        int lr = mt*128 + rbase + r;
        if (lr < cnt && off + lr < TASS){
          float v = acc[fm][fn][r];
          if (kseg == 0) v += be[lc];           // bias exactly once per output
          if (RELU_BF16){
            v = fmaxf(v, 0.f);
            outbf[(size_t)(off + lr)*NDIM + nt*128 + lc] = f2bfu(v);
          } else {
            outseg[(size_t)(off + lr)*NDIM + nt*128 + lc] = v;
          }
        }
      }
    }
  }
}

// ---------- combine: out[t] = p0*(ye0+ye1)[pos0] + p1*(ye0+ye1)[pos1] ----------
__global__ __launch_bounds__(256) void combine_kernel(const float* __restrict__ y0,
    const int* __restrict__ tokpos, const float* __restrict__ top2p,
    float* __restrict__ out, int ks2){
  int i = blockIdx.x*256 + threadIdx.x;   // over TT*TD/4 (exact)
  int t  = i / (TD/4);
  int dc = i % (TD/4);
  int pa = tokpos[t*2], pb = tokpos[t*2+1];
  pa = (pa >= 0 && pa < TASS) ? pa : 0;   // defensive clamp
  pb = (pb >= 0 && pb < TASS) ? pb : 0;
  float wa = top2p[t*2], wb = top2p[t*2+1];
  float4 ya = reinterpret_cast<const float4*>(y0)[(size_t)pa*(TD/4) + dc];
  float4 yb = reinterpret_cast<const float4*>(y0)[(size_t)pb*(TD/4) + dc];
  if (ks2){
    const float* y1 = y0 + (size_t)TASS*TD;
    float4 za = reinterpret_cast<const float4*>(y1)[(size_t)pa*(TD/4) + dc];
    float4 zb = reinterpret_cast<const float4*>(y1)[(size_t)pb*(TD/4) + dc];
    ya.x += za.x; ya.y += za.y; ya.z += za.z; ya.w += za.w;
    yb.x += zb.x; yb.y += zb.y; yb.z += zb.z; yb.w += zb.w;
  }
  float4 o;
  o.x = wa*ya.x + wb*yb.x;
  o.y = wa*ya.y + wb*yb.y;
  o.z = wa*ya.z + wb*yb.z;
  o.w = wa*ya.w + wb*yb.w;
  reinterpret_cast<float4*>(out)[i] = o;
}

extern "C" void kernel_launch(void* const* d_in, const int* in_sizes, int n_in,
                              void* d_out, int out_size, void* d_ws, size_t ws_size,
                              hipStream_t stream){
  const float* x     = (const float*)d_in[0];
  const float* noise = (const float*)d_in[1];
  const float* Wg    = (const float*)d_in[2];
  const float* bg    = (const float*)d_in[3];
  const float* Wn    = (const float*)d_in[4];
  const float* bn    = (const float*)d_in[5];
  const float* W1    = (const float*)d_in[6];
  const float* b1    = (const float*)d_in[7];
  const float* W2    = (const float*)d_in[8];
  const float* b2    = (const float*)d_in[9];
  float* out = (float*)d_out;

  // Static workspace budget (all sizes multiples of 256 -> allocator adds no gaps):
  constexpr size_t SZ_XB   = (size_t)TT*TD*2;
  constexpr size_t SZ_W1T  = (size_t)TE*TH*TD*2;
  constexpr size_t SZ_W2T  = (size_t)TE*TD*TH*2;
  constexpr size_t SZ_HID  = (size_t)TASS*TH*2;
  constexpr size_t SZ_YE   = (size_t)TASS*TD*4;
  constexpr size_t SZ_SMALL= 2*256 + 4*((size_t)TT*2*4);
  constexpr size_t BASE_NEED = SZ_XB+SZ_W1T+SZ_W2T+SZ_HID+SZ_YE+SZ_SMALL + 4096;
  const int ks2 = (BASE_NEED + SZ_YE <= ws_size) ? 1 : 0;   // ws_size-only -> graph-safe

  char* p = (char*)d_ws;
  auto alloc = [&](size_t bytes)->void*{
    void* r = (void*)p;
    p += (bytes + 255) & ~(size_t)255;
    return r;
  };
  unsigned short* xb  = (unsigned short*)alloc(SZ_XB);
  unsigned short* W1t = (unsigned short*)alloc(SZ_W1T);
  unsigned short* W2t = (unsigned short*)alloc(SZ_W2T);
  unsigned short* hid = (unsigned short*)alloc(SZ_HID);
  float* ye           = (float*)alloc(ks2 ? 2*SZ_YE : SZ_YE);  // kseg partials CONTIGUOUS
  int* counts  = (int*)alloc(TE*4);
  int* offs    = (int*)alloc((TE+1)*4);
  int* top2i   = (int*)alloc((size_t)TT*2*4);
  float* top2p = (float*)alloc((size_t)TT*2*4);
  int* rowlist = (int*)alloc((size_t)TASS*4);
  int* tokpos  = (int*)alloc((size_t)TT*2*4);
  if ((size_t)(p - (char*)d_ws) > ws_size) return;  // base layout must fit

  cvt_x_kernel<<<TT*TD/4/256, 256, 0, stream>>>(x, xb);
  transpose_cvt_kernel<<<dim3(TH/32, TD/32, TE), dim3(32,8), 0, stream>>>(W1, W1t, TD, TH);
  transpose_cvt_kernel<<<dim3(TD/32, TH/32, TE), dim3(32,8), 0, stream>>>(W2, W2t, TH, TD);
  gating_kernel<<<TT/4, 256, 0, stream>>>(x, noise, Wg, bg, Wn, bn, top2i, top2p);
  route_kernel<<<1, 512, 0, stream>>>(top2i, counts, offs, rowlist, tokpos);

  gemm_moe<TD, TH, 1, true,  true ><<<dim3(TH/128, 32, TE), 256, 0, stream>>>(
      xb, W1t, b1, rowlist, offs, counts, hid, nullptr);
  if (ks2){
    gemm_moe<TH, TD, 2, false, false><<<dim3(TD/128, 32, TE*2), 256, 0, stream>>>(
        hid, W2t, b2, nullptr, offs, counts, nullptr, ye);
  } else {
    gemm_moe<TH, TD, 1, false, false><<<dim3(TD/128, 32, TE), 256, 0, stream>>>(
        hid, W2t, b2, nullptr, offs, counts, nullptr, ye);
  }

  combine_kernel<<<TT*TD/4/256, 256, 0, stream>>>(ye, tokpos, top2p, out, ks2);
}